// Round 11
// baseline (185.561 us; speedup 1.0000x reference)
//
#include <hip/hip_runtime.h>
#include <hip/hip_bf16.h>

#define C 1000
#define D 128
#define PAD 16            // one atomic target per 64B line

// Phase 1+2 fused: histogram (LDS u32 atomics) + exclusive scan by the
// last-finishing block (atomic ticket; runs exactly once -> deterministic).
__global__ __launch_bounds__(1024)
void k_hist_scan(const int* __restrict__ tgt, unsigned* __restrict__ counts,
                 int* __restrict__ off, int* __restrict__ cursor,
                 unsigned* __restrict__ done, int N) {
    __shared__ unsigned lh[C];
    __shared__ unsigned a[1024];
    __shared__ unsigned is_last;
    const int t = threadIdx.x;
    if (t < C) lh[t] = 0u;
    __syncthreads();
    for (int i = blockIdx.x * 1024 + t; i < N; i += gridDim.x * 1024)
        atomicAdd(&lh[tgt[i]], 1u);
    __syncthreads();
    if (t < C) atomicAdd(&counts[t * PAD], lh[t]);
    __threadfence();
    if (t == 0) is_last = (atomicAdd(done, 1u) == gridDim.x - 1) ? 1u : 0u;
    __syncthreads();
    if (!is_last) return;
    // all other blocks' counts-atomics are fenced-visible here
    const unsigned mine = (t < C) ? *(volatile unsigned*)&counts[t * PAD] : 0u;
    a[t] = mine;
    for (int o = 1; o < 1024; o <<= 1) {
        __syncthreads();
        const unsigned v = (t >= o) ? a[t - o] : 0u;
        __syncthreads();
        a[t] += v;
    }
    __syncthreads();
    if (t < C) {
        const unsigned excl = a[t] - mine;
        off[t] = (int)excl;
        cursor[t * PAD] = (int)excl;
    }
}

// Phase 3: scatter row indices into class-grouped order[].
__global__ __launch_bounds__(256)
void k_scatter(const int* __restrict__ tgt, int* __restrict__ cursor,
               int* __restrict__ order, int N) {
    const int i = blockIdx.x * 256 + threadIdx.x;
    if (i >= N) return;
    const int c = tgt[i];
    const int pos = atomicAdd(&cursor[c * PAD], 1);
    order[pos] = i;
}

// Phase 4 (fused, CHAMPION round-9 form — unchanged): one block per class.
//   A: sum rows (half-wave = one 512B row, 8 rows in flight) -> mean in LDS.
//   B: free-running re-gather (LLC-hot), 4 rows + interleaved shfl chains.
__global__ __launch_bounds__(512)
void k_fused(const float* __restrict__ emb, const int* __restrict__ order,
             const int* __restrict__ off, const unsigned* __restrict__ counts,
             float* __restrict__ percls) {
    __shared__ float part[8][D];
    __shared__ float mean_l[D];
    __shared__ float nacc[16];
    const int c    = blockIdx.x;
    const int t    = threadIdx.x;
    const int w    = t >> 6;            // wave 0..7
    const int lane = t & 63;
    const int half = lane >> 5;
    const int sub  = lane & 31;         // float4 column group 0..31
    const int hw   = t >> 5;            // half-wave 0..15
    const int start = off[c];
    const int cnt   = (int)counts[c * PAD];

    // ---- pass A: class sum, 8 rows in flight per half-wave ----
    const int chunkA = (cnt + 7) >> 3;
    const int wsrt   = start + w * chunkA;
    const int wend   = min(start + cnt, wsrt + chunkA);
    float ax = 0.f, ay = 0.f, az = 0.f, aw = 0.f;
    int pos = wsrt + half;
    for (; pos + 14 < wend; pos += 16) {
        const int r0 = order[pos];      const int r1 = order[pos + 2];
        const int r2 = order[pos + 4];  const int r3 = order[pos + 6];
        const int r4 = order[pos + 8];  const int r5 = order[pos + 10];
        const int r6 = order[pos + 12]; const int r7 = order[pos + 14];
        const float4 v0 = *reinterpret_cast<const float4*>(emb + (size_t)r0 * D + sub * 4);
        const float4 v1 = *reinterpret_cast<const float4*>(emb + (size_t)r1 * D + sub * 4);
        const float4 v2 = *reinterpret_cast<const float4*>(emb + (size_t)r2 * D + sub * 4);
        const float4 v3 = *reinterpret_cast<const float4*>(emb + (size_t)r3 * D + sub * 4);
        const float4 v4 = *reinterpret_cast<const float4*>(emb + (size_t)r4 * D + sub * 4);
        const float4 v5 = *reinterpret_cast<const float4*>(emb + (size_t)r5 * D + sub * 4);
        const float4 v6 = *reinterpret_cast<const float4*>(emb + (size_t)r6 * D + sub * 4);
        const float4 v7 = *reinterpret_cast<const float4*>(emb + (size_t)r7 * D + sub * 4);
        ax += (v0.x + v1.x) + (v2.x + v3.x) + (v4.x + v5.x) + (v6.x + v7.x);
        ay += (v0.y + v1.y) + (v2.y + v3.y) + (v4.y + v5.y) + (v6.y + v7.y);
        az += (v0.z + v1.z) + (v2.z + v3.z) + (v4.z + v5.z) + (v6.z + v7.z);
        aw += (v0.w + v1.w) + (v2.w + v3.w) + (v4.w + v5.w) + (v6.w + v7.w);
    }
    for (; pos < wend; pos += 2) {
        const int r0 = order[pos];
        const float4 v0 = *reinterpret_cast<const float4*>(emb + (size_t)r0 * D + sub * 4);
        ax += v0.x; ay += v0.y; az += v0.z; aw += v0.w;
    }
    ax += __shfl_xor(ax, 32);
    ay += __shfl_xor(ay, 32);
    az += __shfl_xor(az, 32);
    aw += __shfl_xor(aw, 32);
    if (half == 0) {
        part[w][sub * 4 + 0] = ax;
        part[w][sub * 4 + 1] = ay;
        part[w][sub * 4 + 2] = az;
        part[w][sub * 4 + 3] = aw;
    }
    __syncthreads();
    if (t < D) {
        float s = 0.f;
        #pragma unroll
        for (int k = 0; k < 8; ++k) s += part[k][t];
        mean_l[t] = s / fmaxf((float)cnt, 1.f);
    }
    __syncthreads();

    // ---- pass B: 4 rows in flight, 4 interleaved shfl chains ----
    const float4 m = *reinterpret_cast<const float4*>(mean_l + sub * 4);
    const int end = start + cnt;
    float local = 0.f;
    int q = start + hw;
    for (; q + 48 < end; q += 64) {
        const int r0 = order[q];
        const int r1 = order[q + 16];
        const int r2 = order[q + 32];
        const int r3 = order[q + 48];
        const float4 v0 = *reinterpret_cast<const float4*>(emb + (size_t)r0 * D + sub * 4);
        const float4 v1 = *reinterpret_cast<const float4*>(emb + (size_t)r1 * D + sub * 4);
        const float4 v2 = *reinterpret_cast<const float4*>(emb + (size_t)r2 * D + sub * 4);
        const float4 v3 = *reinterpret_cast<const float4*>(emb + (size_t)r3 * D + sub * 4);
        float dx, dy, dz, dw;
        dx = v0.x - m.x; dy = v0.y - m.y; dz = v0.z - m.z; dw = v0.w - m.w;
        float p0 = dx * dx + dy * dy + dz * dz + dw * dw;
        dx = v1.x - m.x; dy = v1.y - m.y; dz = v1.z - m.z; dw = v1.w - m.w;
        float p1 = dx * dx + dy * dy + dz * dz + dw * dw;
        dx = v2.x - m.x; dy = v2.y - m.y; dz = v2.z - m.z; dw = v2.w - m.w;
        float p2 = dx * dx + dy * dy + dz * dz + dw * dw;
        dx = v3.x - m.x; dy = v3.y - m.y; dz = v3.z - m.z; dw = v3.w - m.w;
        float p3 = dx * dx + dy * dy + dz * dz + dw * dw;
        p0 += __shfl_xor(p0, 1);  p1 += __shfl_xor(p1, 1);  p2 += __shfl_xor(p2, 1);  p3 += __shfl_xor(p3, 1);
        p0 += __shfl_xor(p0, 2);  p1 += __shfl_xor(p1, 2);  p2 += __shfl_xor(p2, 2);  p3 += __shfl_xor(p3, 2);
        p0 += __shfl_xor(p0, 4);  p1 += __shfl_xor(p1, 4);  p2 += __shfl_xor(p2, 4);  p3 += __shfl_xor(p3, 4);
        p0 += __shfl_xor(p0, 8);  p1 += __shfl_xor(p1, 8);  p2 += __shfl_xor(p2, 8);  p3 += __shfl_xor(p3, 8);
        p0 += __shfl_xor(p0, 16); p1 += __shfl_xor(p1, 16); p2 += __shfl_xor(p2, 16); p3 += __shfl_xor(p3, 16);
        if (sub == 0) local += (sqrtf(p0) + sqrtf(p1)) + (sqrtf(p2) + sqrtf(p3));
    }
    for (; q < end; q += 16) {
        const int r0 = order[q];
        const float4 v0 = *reinterpret_cast<const float4*>(emb + (size_t)r0 * D + sub * 4);
        const float dx = v0.x - m.x, dy = v0.y - m.y, dz = v0.z - m.z, dw = v0.w - m.w;
        float p0 = dx * dx + dy * dy + dz * dz + dw * dw;
        p0 += __shfl_xor(p0, 1);
        p0 += __shfl_xor(p0, 2);
        p0 += __shfl_xor(p0, 4);
        p0 += __shfl_xor(p0, 8);
        p0 += __shfl_xor(p0, 16);
        if (sub == 0) local += sqrtf(p0);
    }
    if (sub == 0) nacc[hw] = local;
    __syncthreads();
    if (t == 0) {
        float tot = 0.f;
        #pragma unroll
        for (int k = 0; k < 16; ++k) tot += nacc[k];
        percls[c] = (cnt > 0) ? tot / (float)cnt : 0.f;
    }
}

// Phase 5: final scalar = sum of per-class means of norms.
__global__ __launch_bounds__(256)
void k_final(const float* __restrict__ percls, float* __restrict__ out) {
    __shared__ float red[256];
    float acc = 0.f;
    for (int c = threadIdx.x; c < C; c += 256) acc += percls[c];
    red[threadIdx.x] = acc;
    __syncthreads();
    for (int s = 128; s > 0; s >>= 1) {
        if (threadIdx.x < s) red[threadIdx.x] += red[threadIdx.x + s];
        __syncthreads();
    }
    if (threadIdx.x == 0) out[0] = red[0];
}

extern "C" void kernel_launch(void* const* d_in, const int* in_sizes, int n_in,
                              void* d_out, int out_size, void* d_ws, size_t ws_size,
                              hipStream_t stream) {
    const float* emb = (const float*)d_in[0];
    const int*   tgt = (const int*)d_in[1];
    const int N = in_sizes[1];

    char* ws = (char*)d_ws;
    unsigned* counts = (unsigned*)(ws);            // C*PAD u32 = 64000 B (zeroed)
    unsigned* done   = (unsigned*)(ws + 64000);    // 1 u32 ticket (zeroed)
    int*      off    = (int*)(ws + 65536);         // C ints
    float*    percls = (float*)(ws + 73728);       // C f32
    int*      cursor = (int*)(ws + 131072);        // C*PAD ints
    int*      order  = (int*)(ws + 262144);        // N ints = 2 MB

    hipMemsetAsync(d_ws, 0, 64004, stream);        // counts + done

    k_hist_scan<<<256, 1024, 0, stream>>>(tgt, counts, off, cursor, done, N);
    k_scatter<<<(N + 255) / 256, 256, 0, stream>>>(tgt, cursor, order, N);
    k_fused<<<C, 512, 0, stream>>>(emb, order, off, counts, percls);
    k_final<<<1, 256, 0, stream>>>(percls, (float*)d_out);
}

// Round 12
// 133.378 us; speedup vs baseline: 1.3912x; 1.3912x over previous
//
#include <hip/hip_runtime.h>
#include <hip/hip_bf16.h>

#define C 1000
#define D 128
#define PAD 16            // one atomic target per 64B line

// Phase 1: histogram of target classes (LDS u32 atomics -> native ds_add).
__global__ __launch_bounds__(1024)
void k_hist(const int* __restrict__ tgt, unsigned* __restrict__ counts, int N) {
    __shared__ unsigned lh[C];
    const int t = threadIdx.x;
    if (t < C) lh[t] = 0u;
    __syncthreads();
    for (int i = blockIdx.x * 1024 + t; i < N; i += gridDim.x * 1024)
        atomicAdd(&lh[tgt[i]], 1u);
    __syncthreads();
    if (t < C) atomicAdd(&counts[t * PAD], lh[t]);
}

// Phase 2: exclusive scan over 1000 counts -> offsets + scatter cursors.
__global__ __launch_bounds__(1024)
void k_scan(const unsigned* __restrict__ counts, int* __restrict__ off,
            int* __restrict__ cursor) {
    __shared__ unsigned a[1024];
    const int t = threadIdx.x;
    const unsigned mine = (t < C) ? counts[t * PAD] : 0u;
    a[t] = mine;
    for (int o = 1; o < 1024; o <<= 1) {
        __syncthreads();
        const unsigned v = (t >= o) ? a[t - o] : 0u;
        __syncthreads();
        a[t] += v;
    }
    __syncthreads();
    if (t < C) {
        const unsigned excl = a[t] - mine;
        off[t] = (int)excl;
        cursor[t * PAD] = (int)excl;
    }
}

// Phase 3: scatter row indices into class-grouped order[].
__global__ __launch_bounds__(256)
void k_scatter(const int* __restrict__ tgt, int* __restrict__ cursor,
               int* __restrict__ order, int N) {
    const int i = blockIdx.x * 256 + threadIdx.x;
    if (i >= N) return;
    const int c = tgt[i];
    const int pos = atomicAdd(&cursor[c * PAD], 1);
    order[pos] = i;
}

// Phase 4 (fused): one block per class.
//   A: sum class rows (half-wave = one 512B row, 2 in flight) -> mean in LDS.
//   B: free-running re-gather of the same rows (LLC-hot; round-8 FETCH=268MB
//      proved the second read is cache-absorbed), 2 rows with interleaved
//      shfl chains. Deeper unrolls measured equivalent (rounds 8-9).
__global__ __launch_bounds__(512)
void k_fused(const float* __restrict__ emb, const int* __restrict__ order,
             const int* __restrict__ off, const unsigned* __restrict__ counts,
             float* __restrict__ percls) {
    __shared__ float part[8][D];
    __shared__ float mean_l[D];
    __shared__ float nacc[16];
    const int c    = blockIdx.x;
    const int t    = threadIdx.x;
    const int w    = t >> 6;            // wave 0..7
    const int lane = t & 63;
    const int half = lane >> 5;
    const int sub  = lane & 31;         // float4 column group 0..31
    const int hw   = t >> 5;            // half-wave 0..15
    const int start = off[c];
    const int cnt   = (int)counts[c * PAD];

    // ---- pass A: class sum, 2 rows in flight per half-wave ----
    const int chunk = (cnt + 7) >> 3;
    const int wsrt  = start + w * chunk;
    const int wend  = min(start + cnt, wsrt + chunk);
    float ax = 0.f, ay = 0.f, az = 0.f, aw = 0.f;
    int pos = wsrt + half;
    for (; pos + 2 < wend; pos += 4) {
        const int r0 = order[pos];
        const int r1 = order[pos + 2];
        const float4 v0 = *reinterpret_cast<const float4*>(emb + (size_t)r0 * D + sub * 4);
        const float4 v1 = *reinterpret_cast<const float4*>(emb + (size_t)r1 * D + sub * 4);
        ax += v0.x; ay += v0.y; az += v0.z; aw += v0.w;
        ax += v1.x; ay += v1.y; az += v1.z; aw += v1.w;
    }
    for (; pos < wend; pos += 2) {
        const int r0 = order[pos];
        const float4 v0 = *reinterpret_cast<const float4*>(emb + (size_t)r0 * D + sub * 4);
        ax += v0.x; ay += v0.y; az += v0.z; aw += v0.w;
    }
    ax += __shfl_xor(ax, 32);
    ay += __shfl_xor(ay, 32);
    az += __shfl_xor(az, 32);
    aw += __shfl_xor(aw, 32);
    if (half == 0) {
        part[w][sub * 4 + 0] = ax;
        part[w][sub * 4 + 1] = ay;
        part[w][sub * 4 + 2] = az;
        part[w][sub * 4 + 3] = aw;
    }
    __syncthreads();
    if (t < D) {
        float s = 0.f;
        #pragma unroll
        for (int k = 0; k < 8; ++k) s += part[k][t];
        mean_l[t] = s / fmaxf((float)cnt, 1.f);
    }
    __syncthreads();

    // ---- pass B: 2 rows in flight, interleaved shfl chains ----
    const float4 m = *reinterpret_cast<const float4*>(mean_l + sub * 4);
    const int end = start + cnt;
    float local = 0.f;
    int q = start + hw;
    for (; q + 16 < end; q += 32) {
        const int r0 = order[q];
        const int r1 = order[q + 16];
        const float4 v0 = *reinterpret_cast<const float4*>(emb + (size_t)r0 * D + sub * 4);
        const float4 v1 = *reinterpret_cast<const float4*>(emb + (size_t)r1 * D + sub * 4);
        float dx, dy, dz, dw;
        dx = v0.x - m.x; dy = v0.y - m.y; dz = v0.z - m.z; dw = v0.w - m.w;
        float p0 = dx * dx + dy * dy + dz * dz + dw * dw;
        dx = v1.x - m.x; dy = v1.y - m.y; dz = v1.z - m.z; dw = v1.w - m.w;
        float p1 = dx * dx + dy * dy + dz * dz + dw * dw;
        p0 += __shfl_xor(p0, 1);  p1 += __shfl_xor(p1, 1);
        p0 += __shfl_xor(p0, 2);  p1 += __shfl_xor(p1, 2);
        p0 += __shfl_xor(p0, 4);  p1 += __shfl_xor(p1, 4);
        p0 += __shfl_xor(p0, 8);  p1 += __shfl_xor(p1, 8);
        p0 += __shfl_xor(p0, 16); p1 += __shfl_xor(p1, 16);
        if (sub == 0) local += sqrtf(p0) + sqrtf(p1);
    }
    for (; q < end; q += 16) {
        const int r0 = order[q];
        const float4 v0 = *reinterpret_cast<const float4*>(emb + (size_t)r0 * D + sub * 4);
        const float dx = v0.x - m.x, dy = v0.y - m.y, dz = v0.z - m.z, dw = v0.w - m.w;
        float p0 = dx * dx + dy * dy + dz * dz + dw * dw;
        p0 += __shfl_xor(p0, 1);
        p0 += __shfl_xor(p0, 2);
        p0 += __shfl_xor(p0, 4);
        p0 += __shfl_xor(p0, 8);
        p0 += __shfl_xor(p0, 16);
        if (sub == 0) local += sqrtf(p0);
    }
    if (sub == 0) nacc[hw] = local;
    __syncthreads();
    if (t == 0) {
        float tot = 0.f;
        #pragma unroll
        for (int k = 0; k < 16; ++k) tot += nacc[k];
        percls[c] = (cnt > 0) ? tot / (float)cnt : 0.f;
    }
}

// Phase 5: final scalar = sum of per-class means of norms.
__global__ __launch_bounds__(256)
void k_final(const float* __restrict__ percls, float* __restrict__ out) {
    __shared__ float red[256];
    float acc = 0.f;
    for (int c = threadIdx.x; c < C; c += 256) acc += percls[c];
    red[threadIdx.x] = acc;
    __syncthreads();
    for (int s = 128; s > 0; s >>= 1) {
        if (threadIdx.x < s) red[threadIdx.x] += red[threadIdx.x + s];
        __syncthreads();
    }
    if (threadIdx.x == 0) out[0] = red[0];
}

extern "C" void kernel_launch(void* const* d_in, const int* in_sizes, int n_in,
                              void* d_out, int out_size, void* d_ws, size_t ws_size,
                              hipStream_t stream) {
    const float* emb = (const float*)d_in[0];
    const int*   tgt = (const int*)d_in[1];
    const int N = in_sizes[1];

    char* ws = (char*)d_ws;
    unsigned* counts = (unsigned*)(ws);            // C*PAD u32 (zeroed)
    int*      off    = (int*)(ws + 65536);         // C ints
    float*    percls = (float*)(ws + 73728);       // C f32
    int*      cursor = (int*)(ws + 131072);        // C*PAD ints
    int*      order  = (int*)(ws + 262144);        // N ints = 2 MB

    hipMemsetAsync(d_ws, 0, 65536, stream);        // counts only

    k_hist<<<256, 1024, 0, stream>>>(tgt, counts, N);
    k_scan<<<1, 1024, 0, stream>>>(counts, off, cursor);
    k_scatter<<<(N + 255) / 256, 256, 0, stream>>>(tgt, cursor, order, N);
    k_fused<<<C, 512, 0, stream>>>(emb, order, off, counts, percls);
    k_final<<<1, 256, 0, stream>>>(percls, (float*)d_out);
}